// Round 3
// baseline (1286.433 us; speedup 1.0000x reference)
//
#include <hip/hip_runtime.h>
#include <math.h>

#define T_TOK 8192
#define DDIM  1024
#define HDIM  4096
#define NEXP  8
#define BM    256
#define MAXROWS (T_TOK*2 + NEXP*BM)   /* 18432 */
#define MAXTILES (MAXROWS/BM)         /* 72 */
#define LDA   40                      /* LDS row stride in shorts: 80B = 5*16B, 16B-aligned b128 */

typedef __attribute__((ext_vector_type(8))) short short8;
typedef __attribute__((ext_vector_type(4))) short short4v;
typedef __attribute__((ext_vector_type(4))) float f32x4;

__device__ __forceinline__ short f2bf(float f) {
  unsigned u = __float_as_uint(f);
  u += 0x7fffu + ((u >> 16) & 1u);   // RNE
  return (short)(u >> 16);
}

// ---------------- x fp32 -> bf16 ----------------
__global__ __launch_bounds__(256) void k_xb(const float* __restrict__ x,
                                            short* __restrict__ xb) {
  size_t i = ((size_t)blockIdx.x * 256 + threadIdx.x) * 8;
  float4 f0 = *(const float4*)&x[i];
  float4 f1 = *(const float4*)&x[i + 4];
  short8 s;
  s[0]=f2bf(f0.x); s[1]=f2bf(f0.y); s[2]=f2bf(f0.z); s[3]=f2bf(f0.w);
  s[4]=f2bf(f1.x); s[5]=f2bf(f1.y); s[6]=f2bf(f1.z); s[7]=f2bf(f1.w);
  *(short8*)&xb[i] = s;
}

// ---------------- weight transpose + fp32->bf16: wt[e][c][r] = w[e][r][c] ----------------
__global__ __launch_bounds__(256) void k_tr(const float* __restrict__ w,
                                            short* __restrict__ wt, int R, int C) {
  __shared__ float sl[64][65];
  int e = blockIdx.z;
  const float* W = w + (size_t)e * R * C;
  short* O = wt + (size_t)e * R * C;
  int c0 = blockIdx.x * 64, r0 = blockIdx.y * 64;
  int t = threadIdx.x;
  int lr = t >> 4, lc4 = (t & 15) * 4;
#pragma unroll
  for (int i = 0; i < 4; i++) {
    float4 v = *(const float4*)&W[(size_t)(r0 + lr + i * 16) * C + c0 + lc4];
    sl[lr + i * 16][lc4 + 0] = v.x;
    sl[lr + i * 16][lc4 + 1] = v.y;
    sl[lr + i * 16][lc4 + 2] = v.z;
    sl[lr + i * 16][lc4 + 3] = v.w;
  }
  __syncthreads();
#pragma unroll
  for (int i = 0; i < 4; i++) {
    int oc = lr + i * 16;
    short4v s;
#pragma unroll
    for (int j = 0; j < 4; j++) s[j] = f2bf(sl[lc4 + j][oc]);
    *(short4v*)&O[(size_t)(c0 + oc) * R + r0 + lc4] = s;
  }
}

// ---------------- gating (fp32 x for exact top-k selection) ----------------
__global__ __launch_bounds__(256) void k_gate(const float* __restrict__ x,
    const float* __restrict__ gw, const float* __restrict__ gb,
    int2* __restrict__ toke, float2* __restrict__ tokw, int* __restrict__ cnt) {
  __shared__ float sg[NEXP * DDIM];
  for (int i = threadIdx.x; i < NEXP * DDIM; i += 256) {
    int e = i >> 10, d = i & (DDIM - 1);
    sg[i] = gw[d * NEXP + e];
  }
  __syncthreads();
  int wave = threadIdx.x >> 6, lane = threadIdx.x & 63;
  int tok0 = blockIdx.x * 32;
  for (int tt = wave; tt < 32; tt += 4) {
    int tok = tok0 + tt;
    float p[NEXP];
#pragma unroll
    for (int e = 0; e < NEXP; e++) p[e] = 0.f;
#pragma unroll
    for (int c = 0; c < 4; c++) {
      int d = c * 256 + lane * 4;
      float4 xv = *(const float4*)&x[(size_t)tok * DDIM + d];
#pragma unroll
      for (int e = 0; e < NEXP; e++) {
        float4 g = *(const float4*)&sg[e * DDIM + d];
        p[e] += xv.x * g.x + xv.y * g.y + xv.z * g.z + xv.w * g.w;
      }
    }
#pragma unroll
    for (int off = 32; off; off >>= 1)
#pragma unroll
      for (int e = 0; e < NEXP; e++) p[e] += __shfl_xor(p[e], off);
    if (lane == 0) {
      float l[NEXP];
#pragma unroll
      for (int e = 0; e < NEXP; e++) l[e] = p[e] + gb[e];
      int i0 = 0;
#pragma unroll
      for (int e = 1; e < NEXP; e++) if (l[e] > l[i0]) i0 = e;
      int i1 = (i0 == 0) ? 1 : 0;
#pragma unroll
      for (int e = 0; e < NEXP; e++) if (e != i0 && l[e] > l[i1]) i1 = e;
      float ex = expf(l[i1] - l[i0]);
      float w0 = 1.f / (1.f + ex);
      toke[tok] = make_int2(i0, i1);
      tokw[tok] = make_float2(w0, 1.f - w0);
      atomicAdd(&cnt[i0], 1);
      atomicAdd(&cnt[i1], 1);
    }
  }
}

// ---------------- routing plan ----------------
__global__ void k_plan(const int* __restrict__ cnt, int* __restrict__ pbase,
                       int* __restrict__ texp) {
  if (threadIdx.x == 0 && blockIdx.x == 0) {
    int base = 0;
    for (int e = 0; e < NEXP; e++) {
      pbase[e] = base;
      int pc = (cnt[e] + BM - 1) & ~(BM - 1);
      for (int t = base / BM; t < (base + pc) / BM; ++t) texp[t] = e;
      base += pc;
    }
    for (int t = base / BM; t < MAXTILES; ++t) texp[t] = -1;
  }
}

__global__ __launch_bounds__(256) void k_scatter(const int2* __restrict__ toke,
    const float2* __restrict__ tokw, const int* __restrict__ pbase,
    int* __restrict__ fill, int* __restrict__ rtok, float* __restrict__ rwgt) {
  int tok = blockIdx.x * 256 + threadIdx.x;
  if (tok >= T_TOK) return;
  int2 te = toke[tok];
  float2 tw = tokw[tok];
  int s0 = atomicAdd(&fill[te.x], 1);
  rtok[pbase[te.x] + s0] = tok; rwgt[pbase[te.x] + s0] = tw.x;
  int s1 = atomicAdd(&fill[te.y], 1);
  rtok[pbase[te.y] + s1] = tok; rwgt[pbase[te.y] + s1] = tw.y;
}

// ---------------- stage 1: h = gelu(x @ w1[e] + b1[e]) ----------------
// grid (HDIM/256 = 16, nt), 512 threads (8 waves, 2x4). w1t = [e][n(H)][k(D)] bf16.
__global__ __launch_bounds__(512, 2) void k_ffn1(const short* __restrict__ xb,
    const short* __restrict__ w1t, const float* __restrict__ b1,
    const int* __restrict__ rtok, const int* __restrict__ texp,
    int tile_base, short* __restrict__ hbuf) {
  int tl = blockIdx.y;
  int tm = tile_base + tl;
  int e = texp[tm];
  if (e < 0) return;
  int n0 = blockIdx.x * 256;
  const short* W = w1t + (size_t)e * HDIM * DDIM;
  __shared__ short Al[BM * LDA];
  __shared__ short Bl[BM * LDA];
  int t = threadIdx.x;
  int sr  = t >> 1;           // staging row 0..255 (A and B)
  int ss  = (t & 1) * 16;     // shorts offset 0/16
  int atok = rtok[tm * BM + sr];

  f32x4 acc[8][4];
#pragma unroll
  for (int i = 0; i < 8; i++)
#pragma unroll
    for (int j = 0; j < 4; j++) acc[i][j] = (f32x4){0.f, 0.f, 0.f, 0.f};

  int wid = t >> 6, lane = t & 63;
  int wm = (wid >> 2) * 128, wn = (wid & 3) * 64;
  int lr = lane & 15, kg = lane >> 4;

  for (int kt = 0; kt < DDIM / 32; ++kt) {
    int k0 = kt * 32;
    __syncthreads();
    {
      short8 s0 = {0,0,0,0,0,0,0,0}, s1 = s0;
      if (atok >= 0) {
        const short* xp = &xb[(size_t)atok * DDIM + k0 + ss];
        s0 = *(const short8*)&xp[0];
        s1 = *(const short8*)&xp[8];
      }
      *(short8*)&Al[sr * LDA + ss + 0] = s0;
      *(short8*)&Al[sr * LDA + ss + 8] = s1;
      const short* wp = &W[(size_t)(n0 + sr) * DDIM + k0 + ss];
      *(short8*)&Bl[sr * LDA + ss + 0] = *(const short8*)&wp[0];
      *(short8*)&Bl[sr * LDA + ss + 8] = *(const short8*)&wp[8];
    }
    __syncthreads();
    short8 bg[4];
#pragma unroll
    for (int j = 0; j < 4; j++) bg[j] = *(short8*)&Bl[(wn + j * 16 + lr) * LDA + kg * 8];
#pragma unroll
    for (int i = 0; i < 8; i++) {
      short8 af = *(short8*)&Al[(wm + i * 16 + lr) * LDA + kg * 8];
#pragma unroll
      for (int j = 0; j < 4; j++)
        acc[i][j] = __builtin_amdgcn_mfma_f32_16x16x32_bf16(af, bg[j], acc[i][j], 0, 0, 0);
    }
  }

#pragma unroll
  for (int j = 0; j < 4; j++) {
    int gcol = n0 + wn + j * 16 + lr;
    float bias = b1[e * HDIM + gcol];
#pragma unroll
    for (int i = 0; i < 8; i++) {
      int rl = wm + i * 16 + kg * 4;
#pragma unroll
      for (int r = 0; r < 4; r++) {
        float v = acc[i][j][r] + bias;
        v = 0.5f * v * (1.f + erff(v * 0.70710678118f));
        hbuf[(size_t)(tl * BM + rl + r) * HDIM + gcol] = f2bf(v);
      }
    }
  }
}

// ---------------- stage 2: out[tok] += wgt * (h @ w2[e] + b2[e]) ----------------
// grid (DDIM/256 = 4, nt), 512 threads. w2t = [e][n(D)][k(H)] bf16.
__global__ __launch_bounds__(512, 2) void k_ffn2(const short* __restrict__ hbuf,
    const short* __restrict__ w2t, const float* __restrict__ b2,
    const int* __restrict__ rtok, const float* __restrict__ rwgt,
    const int* __restrict__ texp, int tile_base, float* __restrict__ out) {
  int tl = blockIdx.y;
  int tm = tile_base + tl;
  int e = texp[tm];
  if (e < 0) return;
  int n0 = blockIdx.x * 256;
  const short* W = w2t + (size_t)e * DDIM * HDIM;
  __shared__ short Al[BM * LDA];
  __shared__ short Bl[BM * LDA];
  int t = threadIdx.x;
  int sr  = t >> 1;
  int ss  = (t & 1) * 16;

  f32x4 acc[8][4];
#pragma unroll
  for (int i = 0; i < 8; i++)
#pragma unroll
    for (int j = 0; j < 4; j++) acc[i][j] = (f32x4){0.f, 0.f, 0.f, 0.f};

  int wid = t >> 6, lane = t & 63;
  int wm = (wid >> 2) * 128, wn = (wid & 3) * 64;
  int lr = lane & 15, kg = lane >> 4;

  for (int kt = 0; kt < HDIM / 32; ++kt) {
    int k0 = kt * 32;
    __syncthreads();
    {
      const short* hp = &hbuf[(size_t)(tl * BM + sr) * HDIM + k0 + ss];
      *(short8*)&Al[sr * LDA + ss + 0] = *(const short8*)&hp[0];
      *(short8*)&Al[sr * LDA + ss + 8] = *(const short8*)&hp[8];
      const short* wp = &W[(size_t)(n0 + sr) * HDIM + k0 + ss];
      *(short8*)&Bl[sr * LDA + ss + 0] = *(const short8*)&wp[0];
      *(short8*)&Bl[sr * LDA + ss + 8] = *(const short8*)&wp[8];
    }
    __syncthreads();
    short8 bg[4];
#pragma unroll
    for (int j = 0; j < 4; j++) bg[j] = *(short8*)&Bl[(wn + j * 16 + lr) * LDA + kg * 8];
#pragma unroll
    for (int i = 0; i < 8; i++) {
      short8 af = *(short8*)&Al[(wm + i * 16 + lr) * LDA + kg * 8];
#pragma unroll
      for (int j = 0; j < 4; j++)
        acc[i][j] = __builtin_amdgcn_mfma_f32_16x16x32_bf16(af, bg[j], acc[i][j], 0, 0, 0);
    }
  }

#pragma unroll
  for (int j = 0; j < 4; j++) {
    int gcol = n0 + wn + j * 16 + lr;
    float bias = b2[e * DDIM + gcol];
#pragma unroll
    for (int i = 0; i < 8; i++) {
      int rl = wm + i * 16 + kg * 4;
#pragma unroll
      for (int r = 0; r < 4; r++) {
        int grow = tm * BM + rl + r;
        int tok = rtok[grow];
        if (tok >= 0) {
          float v = (acc[i][j][r] + bias) * rwgt[grow];
          atomicAdd(&out[(size_t)tok * DDIM + gcol], v);
        }
      }
    }
  }
}

extern "C" void kernel_launch(void* const* d_in, const int* in_sizes, int n_in,
                              void* d_out, int out_size, void* d_ws, size_t ws_size,
                              hipStream_t stream) {
  const float* x  = (const float*)d_in[0];
  const float* gw = (const float*)d_in[1];
  const float* gb = (const float*)d_in[2];
  const float* w1 = (const float*)d_in[3];
  const float* b1 = (const float*)d_in[4];
  const float* w2 = (const float*)d_in[5];
  const float* b2 = (const float*)d_in[6];
  float* out = (float*)d_out;
  char* ws = (char*)d_ws;

  // ws layout: 1MB header | w1t 67.1MB | w2t 67.1MB | xb 16.8MB | hbuf (chunked)
  int*    cnt   = (int*)(ws + 0);
  int*    fill  = (int*)(ws + 32);
  int*    pbase = (int*)(ws + 64);
  int*    texp  = (int*)(ws + 128);
  int*    rtok  = (int*)(ws + 1024);
  float*  rwgt  = (float*)(ws + 1024 + (size_t)MAXROWS * 4);
  int2*   toke  = (int2*)(ws + 1024 + (size_t)MAXROWS * 8);
  float2* tokw  = (float2*)(ws + 1024 + (size_t)MAXROWS * 8 + (size_t)T_TOK * 8);
  size_t wbytes = (size_t)NEXP * DDIM * HDIM * 2;
  short*  w1t   = (short*)(ws + (1 << 20));
  short*  w2t   = (short*)(ws + (1 << 20) + wbytes);
  short*  xb    = (short*)(ws + (1 << 20) + 2 * wbytes);
  size_t hoff   = (1 << 20) + 2 * wbytes + (size_t)T_TOK * DDIM * 2;
  short*  hbuf  = (short*)(ws + hoff);

  size_t hcap = ws_size > hoff ? ws_size - hoff : 0;
  int tpc = (int)(hcap / ((size_t)BM * HDIM * 2));   // 2MB per tile of h
  if (tpc < 1) return;
  if (tpc > MAXTILES) tpc = MAXTILES;

  hipMemsetAsync(d_out, 0, (size_t)T_TOK * DDIM * 4, stream);
  hipMemsetAsync(ws, 0, 128, stream);
  hipMemsetAsync(rtok, 0xFF, (size_t)MAXROWS * 4, stream);

  k_tr<<<dim3(HDIM / 64, DDIM / 64, NEXP), 256, 0, stream>>>(w1, w1t, DDIM, HDIM);
  k_tr<<<dim3(DDIM / 64, HDIM / 64, NEXP), 256, 0, stream>>>(w2, w2t, HDIM, DDIM);
  k_xb<<<(T_TOK * DDIM) / (256 * 8), 256, 0, stream>>>(x, xb);

  k_gate<<<256, 256, 0, stream>>>(x, gw, gb, toke, tokw, cnt);
  k_plan<<<1, 64, 0, stream>>>(cnt, pbase, texp);
  k_scatter<<<T_TOK / 256, 256, 0, stream>>>(toke, tokw, pbase, fill, rtok, rwgt);

  for (int base = 0; base < MAXTILES; base += tpc) {
    int nt = MAXTILES - base;
    if (nt > tpc) nt = tpc;
    k_ffn1<<<dim3(HDIM / 256, nt), 512, 0, stream>>>(xb, w1t, b1, rtok, texp, base, hbuf);
    k_ffn2<<<dim3(DDIM / 256, nt), 512, 0, stream>>>(hbuf, w2t, b2, rtok, rwgt, texp, base, out);
  }
}

// Round 4
// 1168.512 us; speedup vs baseline: 1.1009x; 1.1009x over previous
//
#include <hip/hip_runtime.h>
#include <math.h>

#define T_TOK 8192
#define DDIM  1024
#define HDIM  4096
#define NEXP  8
#define BM    256
#define BN1   256
#define MAXROWS (T_TOK*2 + NEXP*BM)   /* 18432 */
#define MAXTILES (MAXROWS/BM)         /* 72 */
#define KS2   2                       /* split-K factor for ffn2 */

typedef __attribute__((ext_vector_type(8))) short short8;
typedef __attribute__((ext_vector_type(4))) short short4v;
typedef __attribute__((ext_vector_type(4))) float f32x4;

typedef const __attribute__((address_space(1))) unsigned int* gp1_t;
typedef __attribute__((address_space(3))) unsigned int* lp3_t;

// async global->LDS, 16B per lane; LDS dest = wave-uniform base + lane*16
__device__ __forceinline__ void gld16(const void* g, void* l) {
  __builtin_amdgcn_global_load_lds((gp1_t)g, (lp3_t)l, 16, 0, 0);
}

__device__ __forceinline__ short f2bf(float f) {
  unsigned u = __float_as_uint(f);
  u += 0x7fffu + ((u >> 16) & 1u);   // RNE
  return (short)(u >> 16);
}

// ---------------- x fp32 -> bf16 ----------------
__global__ __launch_bounds__(256) void k_xb(const float* __restrict__ x,
                                            short* __restrict__ xb) {
  size_t i = ((size_t)blockIdx.x * 256 + threadIdx.x) * 8;
  float4 f0 = *(const float4*)&x[i];
  float4 f1 = *(const float4*)&x[i + 4];
  short8 s;
  s[0]=f2bf(f0.x); s[1]=f2bf(f0.y); s[2]=f2bf(f0.z); s[3]=f2bf(f0.w);
  s[4]=f2bf(f1.x); s[5]=f2bf(f1.y); s[6]=f2bf(f1.z); s[7]=f2bf(f1.w);
  *(short8*)&xb[i] = s;
}

// ---------------- weight transpose + fp32->bf16: wt[e][c][r] = w[e][r][c] ----------------
__global__ __launch_bounds__(256) void k_tr(const float* __restrict__ w,
                                            short* __restrict__ wt, int R, int C) {
  __shared__ float sl[64][65];
  int e = blockIdx.z;
  const float* W = w + (size_t)e * R * C;
  short* O = wt + (size_t)e * R * C;
  int c0 = blockIdx.x * 64, r0 = blockIdx.y * 64;
  int t = threadIdx.x;
  int lr = t >> 4, lc4 = (t & 15) * 4;
#pragma unroll
  for (int i = 0; i < 4; i++) {
    float4 v = *(const float4*)&W[(size_t)(r0 + lr + i * 16) * C + c0 + lc4];
    sl[lr + i * 16][lc4 + 0] = v.x;
    sl[lr + i * 16][lc4 + 1] = v.y;
    sl[lr + i * 16][lc4 + 2] = v.z;
    sl[lr + i * 16][lc4 + 3] = v.w;
  }
  __syncthreads();
#pragma unroll
  for (int i = 0; i < 4; i++) {
    int oc = lr + i * 16;
    short4v s;
#pragma unroll
    for (int j = 0; j < 4; j++) s[j] = f2bf(sl[lc4 + j][oc]);
    *(short4v*)&O[(size_t)(c0 + oc) * R + r0 + lc4] = s;
  }
}

// ---------------- gating (fp32 x for exact top-k selection) ----------------
__global__ __launch_bounds__(256) void k_gate(const float* __restrict__ x,
    const float* __restrict__ gw, const float* __restrict__ gb,
    int2* __restrict__ toke, float2* __restrict__ tokw, int* __restrict__ cnt) {
  __shared__ float sg[NEXP * DDIM];
  for (int i = threadIdx.x; i < NEXP * DDIM; i += 256) {
    int e = i >> 10, d = i & (DDIM - 1);
    sg[i] = gw[d * NEXP + e];
  }
  __syncthreads();
  int wave = threadIdx.x >> 6, lane = threadIdx.x & 63;
  int tok0 = blockIdx.x * 32;
  for (int tt = wave; tt < 32; tt += 4) {
    int tok = tok0 + tt;
    float p[NEXP];
#pragma unroll
    for (int e = 0; e < NEXP; e++) p[e] = 0.f;
#pragma unroll
    for (int c = 0; c < 4; c++) {
      int d = c * 256 + lane * 4;
      float4 xv = *(const float4*)&x[(size_t)tok * DDIM + d];
#pragma unroll
      for (int e = 0; e < NEXP; e++) {
        float4 g = *(const float4*)&sg[e * DDIM + d];
        p[e] += xv.x * g.x + xv.y * g.y + xv.z * g.z + xv.w * g.w;
      }
    }
#pragma unroll
    for (int off = 32; off; off >>= 1)
#pragma unroll
      for (int e = 0; e < NEXP; e++) p[e] += __shfl_xor(p[e], off);
    if (lane == 0) {
      float l[NEXP];
#pragma unroll
      for (int e = 0; e < NEXP; e++) l[e] = p[e] + gb[e];
      int i0 = 0;
#pragma unroll
      for (int e = 1; e < NEXP; e++) if (l[e] > l[i0]) i0 = e;
      int i1 = (i0 == 0) ? 1 : 0;
#pragma unroll
      for (int e = 0; e < NEXP; e++) if (e != i0 && l[e] > l[i1]) i1 = e;
      float ex = expf(l[i1] - l[i0]);
      float w0 = 1.f / (1.f + ex);
      toke[tok] = make_int2(i0, i1);
      tokw[tok] = make_float2(w0, 1.f - w0);
      atomicAdd(&cnt[i0], 1);
      atomicAdd(&cnt[i1], 1);
    }
  }
}

// ---------------- routing plan ----------------
__global__ void k_plan(const int* __restrict__ cnt, int* __restrict__ pbase,
                       int* __restrict__ texp) {
  if (threadIdx.x == 0 && blockIdx.x == 0) {
    int base = 0;
    for (int e = 0; e < NEXP; e++) {
      pbase[e] = base;
      int pc = (cnt[e] + BM - 1) & ~(BM - 1);
      for (int t = base / BM; t < (base + pc) / BM; ++t) texp[t] = e;
      base += pc;
    }
    for (int t = base / BM; t < MAXTILES; ++t) texp[t] = -1;
  }
}

__global__ __launch_bounds__(256) void k_scatter(const int2* __restrict__ toke,
    const float2* __restrict__ tokw, const int* __restrict__ pbase,
    int* __restrict__ fill, int* __restrict__ rtok, float* __restrict__ rwgt) {
  int tok = blockIdx.x * 256 + threadIdx.x;
  if (tok >= T_TOK) return;
  int2 te = toke[tok];
  float2 tw = tokw[tok];
  int s0 = atomicAdd(&fill[te.x], 1);
  rtok[pbase[te.x] + s0] = tok; rwgt[pbase[te.x] + s0] = tw.x;
  int s1 = atomicAdd(&fill[te.y], 1);
  rtok[pbase[te.y] + s1] = tok; rwgt[pbase[te.y] + s1] = tw.y;
}

// ---------------- stage 1: h = gelu(x @ w1[e] + b1[e]) ----------------
// grid (HDIM/256 = 16, nt), 512 threads (8 waves, 2x4). w1t = [e][n(H)][k(D)] bf16.
// 2-phase dbuf pipeline with global_load_lds; linear LDS [256][32] shorts.
__global__ __launch_bounds__(512) void k_ffn1(const short* __restrict__ xb,
    const short* __restrict__ w1t, const float* __restrict__ b1,
    const int* __restrict__ rtok, const int* __restrict__ texp,
    int tile_base, short* __restrict__ hbuf) {
  int tl = blockIdx.y;
  int tm = tile_base + tl;
  int e = texp[tm];
  if (e < 0) return;
  int n0 = blockIdx.x * BN1;
  const short* W = w1t + (size_t)e * HDIM * DDIM;
  __shared__ short Al[2][BM * 32];
  __shared__ short Bl[2][BM * 32];
  int t = threadIdx.x;
  int wid = t >> 6, lane = t & 63;
  int seg0 = wid * 2, seg1 = seg0 + 1;      // 16-row segments
  int r0 = seg0 * 16 + (lane >> 2);         // staging row 0..255
  int r1 = r0 + 16;
  int us = (lane & 3) * 8;                  // short offset within 32-short row
  int ta0 = rtok[tm * BM + r0]; if (ta0 < 0) ta0 = 0;   // pads read row 0 (dropped later)
  int ta1 = rtok[tm * BM + r1]; if (ta1 < 0) ta1 = 0;
  const short* sA0 = xb + (size_t)ta0 * DDIM + us;
  const short* sA1 = xb + (size_t)ta1 * DDIM + us;
  const short* sB0 = W + (size_t)(n0 + r0) * DDIM + us;
  const short* sB1 = W + (size_t)(n0 + r1) * DDIM + us;

  f32x4 acc[8][4];
#pragma unroll
  for (int i = 0; i < 8; i++)
#pragma unroll
    for (int j = 0; j < 4; j++) acc[i][j] = (f32x4){0.f, 0.f, 0.f, 0.f};

  int wm = (wid >> 2) * 128, wn = (wid & 3) * 64;
  int lr = lane & 15, kg = lane >> 4;

#define STAGE1(b, ko) { gld16(sA0 + (ko), &Al[b][seg0 * 512]); \
                        gld16(sA1 + (ko), &Al[b][seg1 * 512]); \
                        gld16(sB0 + (ko), &Bl[b][seg0 * 512]); \
                        gld16(sB1 + (ko), &Bl[b][seg1 * 512]); }

  STAGE1(0, 0);
  asm volatile("s_waitcnt vmcnt(0)" ::: "memory");
  __builtin_amdgcn_s_barrier();
  __builtin_amdgcn_sched_barrier(0);

  const int NK = DDIM / 32;
  for (int kt = 0; kt < NK; ++kt) {
    int b = kt & 1;
    if (kt + 1 < NK) STAGE1(b ^ 1, (kt + 1) * 32);   // prefetch next K-step
    short8 bg[4];
#pragma unroll
    for (int j = 0; j < 4; j++) bg[j] = *(short8*)&Bl[b][(wn + j * 16 + lr) * 32 + kg * 8];
#pragma unroll
    for (int i = 0; i < 8; i++) {
      short8 af = *(short8*)&Al[b][(wm + i * 16 + lr) * 32 + kg * 8];
#pragma unroll
      for (int j = 0; j < 4; j++)
        acc[i][j] = __builtin_amdgcn_mfma_f32_16x16x32_bf16(af, bg[j], acc[i][j], 0, 0, 0);
    }
    __builtin_amdgcn_sched_barrier(0);
    asm volatile("s_waitcnt vmcnt(0)" ::: "memory");
    __builtin_amdgcn_s_barrier();
    __builtin_amdgcn_sched_barrier(0);
  }
#undef STAGE1

#pragma unroll
  for (int j = 0; j < 4; j++) {
    int gcol = n0 + wn + j * 16 + lr;
    float bias = b1[e * HDIM + gcol];
#pragma unroll
    for (int i = 0; i < 8; i++) {
      int rl = wm + i * 16 + kg * 4;
#pragma unroll
      for (int r = 0; r < 4; r++) {
        float v = acc[i][j][r] + bias;
        v = 0.5f * v * (1.f + erff(v * 0.70710678118f));
        hbuf[(size_t)(tl * BM + rl + r) * HDIM + gcol] = f2bf(v);
      }
    }
  }
}

// ---------------- stage 2: out[tok] += wgt * (h @ w2[e] + b2[e]) ----------------
// grid (DDIM/256 = 4, KS2, nt), 512 threads. w2t = [e][n(D)][k(H)] bf16. Split-K over H.
__global__ __launch_bounds__(512) void k_ffn2(const short* __restrict__ hbuf,
    const short* __restrict__ w2t, const float* __restrict__ b2,
    const int* __restrict__ rtok, const float* __restrict__ rwgt,
    const int* __restrict__ texp, int tile_base, float* __restrict__ out) {
  int tl = blockIdx.z;
  int tm = tile_base + tl;
  int e = texp[tm];
  if (e < 0) return;
  int kc = blockIdx.y;
  int n0 = blockIdx.x * BN1;
  const short* W = w2t + (size_t)e * DDIM * HDIM;
  __shared__ short Al[2][BM * 32];
  __shared__ short Bl[2][BM * 32];
  int t = threadIdx.x;
  int wid = t >> 6, lane = t & 63;
  int seg0 = wid * 2, seg1 = seg0 + 1;
  int r0 = seg0 * 16 + (lane >> 2);
  int r1 = r0 + 16;
  int us = (lane & 3) * 8;
  const int NK = HDIM / 32 / KS2;           // 64 K-steps per split
  int kbase = kc * NK * 32;                 // short offset of this split's K range
  const short* sA0 = hbuf + (size_t)(tl * BM + r0) * HDIM + kbase + us;
  const short* sA1 = hbuf + (size_t)(tl * BM + r1) * HDIM + kbase + us;
  const short* sB0 = W + (size_t)(n0 + r0) * HDIM + kbase + us;
  const short* sB1 = W + (size_t)(n0 + r1) * HDIM + kbase + us;

  f32x4 acc[8][4];
#pragma unroll
  for (int i = 0; i < 8; i++)
#pragma unroll
    for (int j = 0; j < 4; j++) acc[i][j] = (f32x4){0.f, 0.f, 0.f, 0.f};

  int wm = (wid >> 2) * 128, wn = (wid & 3) * 64;
  int lr = lane & 15, kg = lane >> 4;

#define STAGE2(b, ko) { gld16(sA0 + (ko), &Al[b][seg0 * 512]); \
                        gld16(sA1 + (ko), &Al[b][seg1 * 512]); \
                        gld16(sB0 + (ko), &Bl[b][seg0 * 512]); \
                        gld16(sB1 + (ko), &Bl[b][seg1 * 512]); }

  STAGE2(0, 0);
  asm volatile("s_waitcnt vmcnt(0)" ::: "memory");
  __builtin_amdgcn_s_barrier();
  __builtin_amdgcn_sched_barrier(0);

  for (int kt = 0; kt < NK; ++kt) {
    int b = kt & 1;
    if (kt + 1 < NK) STAGE2(b ^ 1, (kt + 1) * 32);
    short8 bg[4];
#pragma unroll
    for (int j = 0; j < 4; j++) bg[j] = *(short8*)&Bl[b][(wn + j * 16 + lr) * 32 + kg * 8];
#pragma unroll
    for (int i = 0; i < 8; i++) {
      short8 af = *(short8*)&Al[b][(wm + i * 16 + lr) * 32 + kg * 8];
#pragma unroll
      for (int j = 0; j < 4; j++)
        acc[i][j] = __builtin_amdgcn_mfma_f32_16x16x32_bf16(af, bg[j], acc[i][j], 0, 0, 0);
    }
    __builtin_amdgcn_sched_barrier(0);
    asm volatile("s_waitcnt vmcnt(0)" ::: "memory");
    __builtin_amdgcn_s_barrier();
    __builtin_amdgcn_sched_barrier(0);
  }
#undef STAGE2

#pragma unroll
  for (int j = 0; j < 4; j++) {
    int gcol = n0 + wn + j * 16 + lr;
    float bias = (kc == 0) ? b2[e * DDIM + gcol] : 0.f;
#pragma unroll
    for (int i = 0; i < 8; i++) {
      int rl = wm + i * 16 + kg * 4;
#pragma unroll
      for (int r = 0; r < 4; r++) {
        int grow = tm * BM + rl + r;
        int tok = rtok[grow];
        if (tok >= 0) {
          float v = (acc[i][j][r] + bias) * rwgt[grow];
          atomicAdd(&out[(size_t)tok * DDIM + gcol], v);
        }
      }
    }
  }
}

extern "C" void kernel_launch(void* const* d_in, const int* in_sizes, int n_in,
                              void* d_out, int out_size, void* d_ws, size_t ws_size,
                              hipStream_t stream) {
  const float* x  = (const float*)d_in[0];
  const float* gw = (const float*)d_in[1];
  const float* gb = (const float*)d_in[2];
  const float* w1 = (const float*)d_in[3];
  const float* b1 = (const float*)d_in[4];
  const float* w2 = (const float*)d_in[5];
  const float* b2 = (const float*)d_in[6];
  float* out = (float*)d_out;
  char* ws = (char*)d_ws;

  // ws layout: 1MB header | w1t 67.1MB | w2t 67.1MB | xb 16.8MB | hbuf (chunked)
  int*    cnt   = (int*)(ws + 0);
  int*    fill  = (int*)(ws + 32);
  int*    pbase = (int*)(ws + 64);
  int*    texp  = (int*)(ws + 128);
  int*    rtok  = (int*)(ws + 1024);
  float*  rwgt  = (float*)(ws + 1024 + (size_t)MAXROWS * 4);
  int2*   toke  = (int2*)(ws + 1024 + (size_t)MAXROWS * 8);
  float2* tokw  = (float2*)(ws + 1024 + (size_t)MAXROWS * 8 + (size_t)T_TOK * 8);
  size_t wbytes = (size_t)NEXP * DDIM * HDIM * 2;
  short*  w1t   = (short*)(ws + (1 << 20));
  short*  w2t   = (short*)(ws + (1 << 20) + wbytes);
  short*  xb    = (short*)(ws + (1 << 20) + 2 * wbytes);
  size_t hoff   = (1 << 20) + 2 * wbytes + (size_t)T_TOK * DDIM * 2;
  short*  hbuf  = (short*)(ws + hoff);

  size_t hcap = ws_size > hoff ? ws_size - hoff : 0;
  int tpc = (int)(hcap / ((size_t)BM * HDIM * 2));   // 2MB per tile of h
  if (tpc < 1) return;
  if (tpc > MAXTILES) tpc = MAXTILES;

  hipMemsetAsync(d_out, 0, (size_t)T_TOK * DDIM * 4, stream);
  hipMemsetAsync(ws, 0, 128, stream);
  hipMemsetAsync(rtok, 0xFF, (size_t)MAXROWS * 4, stream);

  k_tr<<<dim3(HDIM / 64, DDIM / 64, NEXP), 256, 0, stream>>>(w1, w1t, DDIM, HDIM);
  k_tr<<<dim3(DDIM / 64, HDIM / 64, NEXP), 256, 0, stream>>>(w2, w2t, HDIM, DDIM);
  k_xb<<<(T_TOK * DDIM) / (256 * 8), 256, 0, stream>>>(x, xb);

  k_gate<<<256, 256, 0, stream>>>(x, gw, gb, toke, tokw, cnt);
  k_plan<<<1, 64, 0, stream>>>(cnt, pbase, texp);
  k_scatter<<<T_TOK / 256, 256, 0, stream>>>(toke, tokw, pbase, fill, rtok, rwgt);

  for (int base = 0; base < MAXTILES; base += tpc) {
    int nt = MAXTILES - base;
    if (nt > tpc) nt = tpc;
    k_ffn1<<<dim3(HDIM / BN1, nt), 512, 0, stream>>>(xb, w1t, b1, rtok, texp, base, hbuf);
    k_ffn2<<<dim3(DDIM / BN1, KS2, nt), 512, 0, stream>>>(hbuf, w2t, b2, rtok, rwgt, texp, base, out);
  }
}

// Round 5
// 1070.265 us; speedup vs baseline: 1.2020x; 1.0918x over previous
//
#include <hip/hip_runtime.h>
#include <math.h>

#define T_TOK 8192
#define DDIM  1024
#define HDIM  4096
#define NEXP  8
#define BM    256
#define BN1   256
#define BK    64                      /* shorts per K-tile */
#define MAXROWS (T_TOK*2 + NEXP*BM)   /* 18432 */
#define MAXTILES (MAXROWS/BM)         /* 72 */
#define KS2   2                       /* split-K factor for ffn2 */

typedef __attribute__((ext_vector_type(8))) short short8;
typedef __attribute__((ext_vector_type(4))) short short4v;
typedef __attribute__((ext_vector_type(4))) float f32x4;

typedef const __attribute__((address_space(1))) unsigned int* gp1_t;
typedef __attribute__((address_space(3))) unsigned int* lp3_t;

// async global->LDS, 16B per lane; LDS dest = wave-uniform base + lane*16
__device__ __forceinline__ void gld16(const void* g, void* l) {
  __builtin_amdgcn_global_load_lds((gp1_t)g, (lp3_t)l, 16, 0, 0);
}

__device__ __forceinline__ short f2bf(float f) {
  unsigned u = __float_as_uint(f);
  u += 0x7fffu + ((u >> 16) & 1u);   // RNE
  return (short)(u >> 16);
}

// ---------------- x fp32 -> bf16 ----------------
__global__ __launch_bounds__(256) void k_xb(const float* __restrict__ x,
                                            short* __restrict__ xb) {
  size_t i = ((size_t)blockIdx.x * 256 + threadIdx.x) * 8;
  float4 f0 = *(const float4*)&x[i];
  float4 f1 = *(const float4*)&x[i + 4];
  short8 s;
  s[0]=f2bf(f0.x); s[1]=f2bf(f0.y); s[2]=f2bf(f0.z); s[3]=f2bf(f0.w);
  s[4]=f2bf(f1.x); s[5]=f2bf(f1.y); s[6]=f2bf(f1.z); s[7]=f2bf(f1.w);
  *(short8*)&xb[i] = s;
}

// ---------------- weight transpose + fp32->bf16: wt[e][c][r] = w[e][r][c] ----------------
__global__ __launch_bounds__(256) void k_tr(const float* __restrict__ w,
                                            short* __restrict__ wt, int R, int C) {
  __shared__ float sl[64][65];
  int e = blockIdx.z;
  const float* W = w + (size_t)e * R * C;
  short* O = wt + (size_t)e * R * C;
  int c0 = blockIdx.x * 64, r0 = blockIdx.y * 64;
  int t = threadIdx.x;
  int lr = t >> 4, lc4 = (t & 15) * 4;
#pragma unroll
  for (int i = 0; i < 4; i++) {
    float4 v = *(const float4*)&W[(size_t)(r0 + lr + i * 16) * C + c0 + lc4];
    sl[lr + i * 16][lc4 + 0] = v.x;
    sl[lr + i * 16][lc4 + 1] = v.y;
    sl[lr + i * 16][lc4 + 2] = v.z;
    sl[lr + i * 16][lc4 + 3] = v.w;
  }
  __syncthreads();
#pragma unroll
  for (int i = 0; i < 4; i++) {
    int oc = lr + i * 16;
    short4v s;
#pragma unroll
    for (int j = 0; j < 4; j++) s[j] = f2bf(sl[lc4 + j][oc]);
    *(short4v*)&O[(size_t)(c0 + oc) * R + r0 + lc4] = s;
  }
}

// ---------------- gating (fp32 x for exact top-k selection) ----------------
__global__ __launch_bounds__(256) void k_gate(const float* __restrict__ x,
    const float* __restrict__ gw, const float* __restrict__ gb,
    int2* __restrict__ toke, float2* __restrict__ tokw, int* __restrict__ cnt) {
  __shared__ float sg[NEXP * DDIM];
  for (int i = threadIdx.x; i < NEXP * DDIM; i += 256) {
    int e = i >> 10, d = i & (DDIM - 1);
    sg[i] = gw[d * NEXP + e];
  }
  __syncthreads();
  int wave = threadIdx.x >> 6, lane = threadIdx.x & 63;
  int tok0 = blockIdx.x * 32;
  for (int tt = wave; tt < 32; tt += 4) {
    int tok = tok0 + tt;
    float p[NEXP];
#pragma unroll
    for (int e = 0; e < NEXP; e++) p[e] = 0.f;
#pragma unroll
    for (int c = 0; c < 4; c++) {
      int d = c * 256 + lane * 4;
      float4 xv = *(const float4*)&x[(size_t)tok * DDIM + d];
#pragma unroll
      for (int e = 0; e < NEXP; e++) {
        float4 g = *(const float4*)&sg[e * DDIM + d];
        p[e] += xv.x * g.x + xv.y * g.y + xv.z * g.z + xv.w * g.w;
      }
    }
#pragma unroll
    for (int off = 32; off; off >>= 1)
#pragma unroll
      for (int e = 0; e < NEXP; e++) p[e] += __shfl_xor(p[e], off);
    if (lane == 0) {
      float l[NEXP];
#pragma unroll
      for (int e = 0; e < NEXP; e++) l[e] = p[e] + gb[e];
      int i0 = 0;
#pragma unroll
      for (int e = 1; e < NEXP; e++) if (l[e] > l[i0]) i0 = e;
      int i1 = (i0 == 0) ? 1 : 0;
#pragma unroll
      for (int e = 0; e < NEXP; e++) if (e != i0 && l[e] > l[i1]) i1 = e;
      float ex = expf(l[i1] - l[i0]);
      float w0 = 1.f / (1.f + ex);
      toke[tok] = make_int2(i0, i1);
      tokw[tok] = make_float2(w0, 1.f - w0);
      atomicAdd(&cnt[i0], 1);
      atomicAdd(&cnt[i1], 1);
    }
  }
}

// ---------------- routing plan ----------------
__global__ void k_plan(const int* __restrict__ cnt, int* __restrict__ pbase,
                       int* __restrict__ texp) {
  if (threadIdx.x == 0 && blockIdx.x == 0) {
    int base = 0;
    for (int e = 0; e < NEXP; e++) {
      pbase[e] = base;
      int pc = (cnt[e] + BM - 1) & ~(BM - 1);
      for (int t = base / BM; t < (base + pc) / BM; ++t) texp[t] = e;
      base += pc;
    }
    for (int t = base / BM; t < MAXTILES; ++t) texp[t] = -1;
  }
}

__global__ __launch_bounds__(256) void k_scatter(const int2* __restrict__ toke,
    const float2* __restrict__ tokw, const int* __restrict__ pbase,
    int* __restrict__ fill, int* __restrict__ rtok, float* __restrict__ rwgt) {
  int tok = blockIdx.x * 256 + threadIdx.x;
  if (tok >= T_TOK) return;
  int2 te = toke[tok];
  float2 tw = tokw[tok];
  int s0 = atomicAdd(&fill[te.x], 1);
  rtok[pbase[te.x] + s0] = tok; rwgt[pbase[te.x] + s0] = tw.x;
  int s1 = atomicAdd(&fill[te.y], 1);
  rtok[pbase[te.y] + s1] = tok; rwgt[pbase[te.y] + s1] = tw.y;
}

// LDS layout (both GEMMs): linear [256 rows][BK=64 shorts]; logical 16B slot s of
// row r holds global slot (s ^ (r&7))  -> bank-conflict-free frag reads (T2, rule #21).
// Staging: wave w, call i covers rows i*64+w*8 .. +7; lane l -> row +(l>>3), slot l&7.

// ---------------- stage 1: h = gelu(x @ w1[e] + b1[e]) ----------------
// grid (HDIM/256 = 16, nt), 512 threads (8 waves, 2x4). w1t = [e][n(H)][k(D)] bf16.
__global__ __launch_bounds__(512) void k_ffn1(const short* __restrict__ xb,
    const short* __restrict__ w1t, const float* __restrict__ b1,
    const int* __restrict__ rtok, const int* __restrict__ texp,
    int tile_base, short* __restrict__ hbuf) {
  int tl = blockIdx.y;
  int tm = tile_base + tl;
  int e = texp[tm];
  if (e < 0) return;
  int n0 = blockIdx.x * BN1;
  const short* W = w1t + (size_t)e * HDIM * DDIM;
  __shared__ short Al[2][BM * BK];
  __shared__ short Bl[2][BM * BK];
  int t = threadIdx.x, wid = t >> 6, lane = t & 63;
  int sr8 = lane >> 3, slot = lane & 7;
  const short* sA[4]; const short* sB[4];
#pragma unroll
  for (int i = 0; i < 4; i++) {
    int r = i * 64 + wid * 8 + sr8;
    int tok = rtok[tm * BM + r]; if (tok < 0) tok = 0;   // pads read row0 (dropped in ffn2)
    sA[i] = xb + (size_t)tok * DDIM + ((slot ^ sr8) * 8);
    sB[i] = W + (size_t)(n0 + r) * DDIM + ((slot ^ sr8) * 8);
  }

  f32x4 acc[8][4];
#pragma unroll
  for (int i = 0; i < 8; i++)
#pragma unroll
    for (int j = 0; j < 4; j++) acc[i][j] = (f32x4){0.f, 0.f, 0.f, 0.f};

  int wm = (wid >> 2) * 128, wn = (wid & 3) * 64;
  int lr = lane & 15, kg = lane >> 4, x7 = lr & 7;

#define STG(b, ko) { \
  gld16(sA[0] + (ko), &Al[b][(0 * 64 + wid * 8) * BK]); \
  gld16(sA[1] + (ko), &Al[b][(1 * 64 + wid * 8) * BK]); \
  gld16(sA[2] + (ko), &Al[b][(2 * 64 + wid * 8) * BK]); \
  gld16(sA[3] + (ko), &Al[b][(3 * 64 + wid * 8) * BK]); \
  gld16(sB[0] + (ko), &Bl[b][(0 * 64 + wid * 8) * BK]); \
  gld16(sB[1] + (ko), &Bl[b][(1 * 64 + wid * 8) * BK]); \
  gld16(sB[2] + (ko), &Bl[b][(2 * 64 + wid * 8) * BK]); \
  gld16(sB[3] + (ko), &Bl[b][(3 * 64 + wid * 8) * BK]); }

  STG(0, 0);
  asm volatile("s_waitcnt vmcnt(0)" ::: "memory");
  __builtin_amdgcn_s_barrier();
  __builtin_amdgcn_sched_barrier(0);

  const int NK = DDIM / BK;     // 16
  for (int kt = 0; kt < NK; ++kt) {
    int b = kt & 1;
    if (kt + 1 < NK) STG(b ^ 1, (kt + 1) * BK);
    __builtin_amdgcn_s_setprio(1);
#pragma unroll
    for (int s = 0; s < 2; ++s) {
      int xo = ((s * 4 + kg) ^ x7) << 3;
      short8 bg[4];
#pragma unroll
      for (int j = 0; j < 4; j++) bg[j] = *(short8*)&Bl[b][(wn + j * 16 + lr) * BK + xo];
#pragma unroll
      for (int i = 0; i < 8; i++) {
        short8 af = *(short8*)&Al[b][(wm + i * 16 + lr) * BK + xo];
#pragma unroll
        for (int j = 0; j < 4; j++)
          acc[i][j] = __builtin_amdgcn_mfma_f32_16x16x32_bf16(af, bg[j], acc[i][j], 0, 0, 0);
      }
    }
    __builtin_amdgcn_s_setprio(0);
    __builtin_amdgcn_sched_barrier(0);
    asm volatile("s_waitcnt vmcnt(0)" ::: "memory");
    __builtin_amdgcn_s_barrier();
    __builtin_amdgcn_sched_barrier(0);
  }

#pragma unroll
  for (int j = 0; j < 4; j++) {
    int gcol = n0 + wn + j * 16 + lr;
    float bias = b1[e * HDIM + gcol];
#pragma unroll
    for (int i = 0; i < 8; i++) {
      int rl = wm + i * 16 + kg * 4;
#pragma unroll
      for (int r = 0; r < 4; r++) {
        float v = acc[i][j][r] + bias;
        v = 0.5f * v * (1.f + erff(v * 0.70710678118f));
        hbuf[(size_t)(tl * BM + rl + r) * HDIM + gcol] = f2bf(v);
      }
    }
  }
}

// ---------------- stage 2: out[tok] += wgt * (h @ w2[e] + b2[e]) ----------------
// grid (DDIM/256 = 4, KS2, nt), 512 threads. w2t = [e][n(D)][k(H)] bf16. Split-K over H.
__global__ __launch_bounds__(512) void k_ffn2(const short* __restrict__ hbuf,
    const short* __restrict__ w2t, const float* __restrict__ b2,
    const int* __restrict__ rtok, const float* __restrict__ rwgt,
    const int* __restrict__ texp, int tile_base, float* __restrict__ out) {
  int tl = blockIdx.z;
  int tm = tile_base + tl;
  int e = texp[tm];
  if (e < 0) return;
  int kc = blockIdx.y;
  int n0 = blockIdx.x * BN1;
  const short* W = w2t + (size_t)e * DDIM * HDIM;
  __shared__ short Al[2][BM * BK];
  __shared__ short Bl[2][BM * BK];
  int t = threadIdx.x, wid = t >> 6, lane = t & 63;
  int sr8 = lane >> 3, slot = lane & 7;
  const int NK = HDIM / BK / KS2;            // 16
  int kbase = kc * NK * BK;
  const short* sA[4]; const short* sB[4];
#pragma unroll
  for (int i = 0; i < 4; i++) {
    int r = i * 64 + wid * 8 + sr8;
    sA[i] = hbuf + (size_t)(tl * BM + r) * HDIM + kbase + ((slot ^ sr8) * 8);
    sB[i] = W + (size_t)(n0 + r) * HDIM + kbase + ((slot ^ sr8) * 8);
  }

  f32x4 acc[8][4];
#pragma unroll
  for (int i = 0; i < 8; i++)
#pragma unroll
    for (int j = 0; j < 4; j++) acc[i][j] = (f32x4){0.f, 0.f, 0.f, 0.f};

  int wm = (wid >> 2) * 128, wn = (wid & 3) * 64;
  int lr = lane & 15, kg = lane >> 4, x7 = lr & 7;

  STG(0, 0);
  asm volatile("s_waitcnt vmcnt(0)" ::: "memory");
  __builtin_amdgcn_s_barrier();
  __builtin_amdgcn_sched_barrier(0);

  for (int kt = 0; kt < NK; ++kt) {
    int b = kt & 1;
    if (kt + 1 < NK) STG(b ^ 1, (kt + 1) * BK);
    __builtin_amdgcn_s_setprio(1);
#pragma unroll
    for (int s = 0; s < 2; ++s) {
      int xo = ((s * 4 + kg) ^ x7) << 3;
      short8 bg[4];
#pragma unroll
      for (int j = 0; j < 4; j++) bg[j] = *(short8*)&Bl[b][(wn + j * 16 + lr) * BK + xo];
#pragma unroll
      for (int i = 0; i < 8; i++) {
        short8 af = *(short8*)&Al[b][(wm + i * 16 + lr) * BK + xo];
#pragma unroll
        for (int j = 0; j < 4; j++)
          acc[i][j] = __builtin_amdgcn_mfma_f32_16x16x32_bf16(af, bg[j], acc[i][j], 0, 0, 0);
      }
    }
    __builtin_amdgcn_s_setprio(0);
    __builtin_amdgcn_sched_barrier(0);
    asm volatile("s_waitcnt vmcnt(0)" ::: "memory");
    __builtin_amdgcn_s_barrier();
    __builtin_amdgcn_sched_barrier(0);
  }
#undef STG

#pragma unroll
  for (int j = 0; j < 4; j++) {
    int gcol = n0 + wn + j * 16 + lr;
    float bias = (kc == 0) ? b2[e * DDIM + gcol] : 0.f;
#pragma unroll
    for (int i = 0; i < 8; i++) {
      int rl = wm + i * 16 + kg * 4;
#pragma unroll
      for (int r = 0; r < 4; r++) {
        int grow = tm * BM + rl + r;
        int tok = rtok[grow];
        if (tok >= 0) {
          float v = (acc[i][j][r] + bias) * rwgt[grow];
          atomicAdd(&out[(size_t)tok * DDIM + gcol], v);
        }
      }
    }
  }
}

extern "C" void kernel_launch(void* const* d_in, const int* in_sizes, int n_in,
                              void* d_out, int out_size, void* d_ws, size_t ws_size,
                              hipStream_t stream) {
  const float* x  = (const float*)d_in[0];
  const float* gw = (const float*)d_in[1];
  const float* gb = (const float*)d_in[2];
  const float* w1 = (const float*)d_in[3];
  const float* b1 = (const float*)d_in[4];
  const float* w2 = (const float*)d_in[5];
  const float* b2 = (const float*)d_in[6];
  float* out = (float*)d_out;
  char* ws = (char*)d_ws;

  // ws layout: 1MB header | w1t 67.1MB | w2t 67.1MB | xb 16.8MB | hbuf (chunked)
  int*    cnt   = (int*)(ws + 0);
  int*    fill  = (int*)(ws + 32);
  int*    pbase = (int*)(ws + 64);
  int*    texp  = (int*)(ws + 128);
  int*    rtok  = (int*)(ws + 1024);
  float*  rwgt  = (float*)(ws + 1024 + (size_t)MAXROWS * 4);
  int2*   toke  = (int2*)(ws + 1024 + (size_t)MAXROWS * 8);
  float2* tokw  = (float2*)(ws + 1024 + (size_t)MAXROWS * 8 + (size_t)T_TOK * 8);
  size_t wbytes = (size_t)NEXP * DDIM * HDIM * 2;
  short*  w1t   = (short*)(ws + (1 << 20));
  short*  w2t   = (short*)(ws + (1 << 20) + wbytes);
  short*  xb    = (short*)(ws + (1 << 20) + 2 * wbytes);
  size_t hoff   = (1 << 20) + 2 * wbytes + (size_t)T_TOK * DDIM * 2;
  short*  hbuf  = (short*)(ws + hoff);

  size_t hcap = ws_size > hoff ? ws_size - hoff : 0;
  int tpc = (int)(hcap / ((size_t)BM * HDIM * 2));   // 2MB per tile of h
  if (tpc < 1) return;
  if (tpc > MAXTILES) tpc = MAXTILES;

  hipMemsetAsync(d_out, 0, (size_t)T_TOK * DDIM * 4, stream);
  hipMemsetAsync(ws, 0, 128, stream);
  hipMemsetAsync(rtok, 0xFF, (size_t)MAXROWS * 4, stream);

  k_tr<<<dim3(HDIM / 64, DDIM / 64, NEXP), 256, 0, stream>>>(w1, w1t, DDIM, HDIM);
  k_tr<<<dim3(DDIM / 64, HDIM / 64, NEXP), 256, 0, stream>>>(w2, w2t, HDIM, DDIM);
  k_xb<<<(T_TOK * DDIM) / (256 * 8), 256, 0, stream>>>(x, xb);

  k_gate<<<256, 256, 0, stream>>>(x, gw, gb, toke, tokw, cnt);
  k_plan<<<1, 64, 0, stream>>>(cnt, pbase, texp);
  k_scatter<<<T_TOK / 256, 256, 0, stream>>>(toke, tokw, pbase, fill, rtok, rwgt);

  for (int base = 0; base < MAXTILES; base += tpc) {
    int nt = MAXTILES - base;
    if (nt > tpc) nt = tpc;
    k_ffn1<<<dim3(HDIM / BN1, nt), 512, 0, stream>>>(xb, w1t, b1, rtok, texp, base, hbuf);
    k_ffn2<<<dim3(DDIM / BN1, KS2, nt), 512, 0, stream>>>(hbuf, w2t, b2, rtok, rwgt, texp, base, out);
  }
}

// Round 6
// 1063.416 us; speedup vs baseline: 1.2097x; 1.0064x over previous
//
#include <hip/hip_runtime.h>
#include <math.h>

#define T_TOK 8192
#define DDIM  1024
#define HDIM  4096
#define NEXP  8
#define BM    256
#define BN1   256
#define BK    64                      /* shorts per K-tile */
#define MAXROWS (T_TOK*2 + NEXP*BM)   /* 18432 */
#define MAXTILES (MAXROWS/BM)         /* 72 */
#define KS2   2                       /* split-K factor for ffn2 */

typedef __attribute__((ext_vector_type(8))) short short8;
typedef __attribute__((ext_vector_type(4))) short short4v;
typedef __attribute__((ext_vector_type(4))) float f32x4;

typedef const __attribute__((address_space(1))) unsigned int* gp1_t;
typedef __attribute__((address_space(3))) unsigned int* lp3_t;

// async global->LDS, 16B per lane; LDS dest = wave-uniform base + lane*16
__device__ __forceinline__ void gld16(const void* g, void* l) {
  __builtin_amdgcn_global_load_lds((gp1_t)g, (lp3_t)l, 16, 0, 0);
}

__device__ __forceinline__ short f2bf(float f) {
  unsigned u = __float_as_uint(f);
  u += 0x7fffu + ((u >> 16) & 1u);   // RNE
  return (short)(u >> 16);
}

// ---------------- x fp32 -> bf16 ----------------
__global__ __launch_bounds__(256) void k_xb(const float* __restrict__ x,
                                            short* __restrict__ xb) {
  size_t i = ((size_t)blockIdx.x * 256 + threadIdx.x) * 8;
  float4 f0 = *(const float4*)&x[i];
  float4 f1 = *(const float4*)&x[i + 4];
  short8 s;
  s[0]=f2bf(f0.x); s[1]=f2bf(f0.y); s[2]=f2bf(f0.z); s[3]=f2bf(f0.w);
  s[4]=f2bf(f1.x); s[5]=f2bf(f1.y); s[6]=f2bf(f1.z); s[7]=f2bf(f1.w);
  *(short8*)&xb[i] = s;
}

// ---------------- weight transpose + fp32->bf16: wt[e][c][r] = w[e][r][c] ----------------
__global__ __launch_bounds__(256) void k_tr(const float* __restrict__ w,
                                            short* __restrict__ wt, int R, int C) {
  __shared__ float sl[64][65];
  int e = blockIdx.z;
  const float* W = w + (size_t)e * R * C;
  short* O = wt + (size_t)e * R * C;
  int c0 = blockIdx.x * 64, r0 = blockIdx.y * 64;
  int t = threadIdx.x;
  int lr = t >> 4, lc4 = (t & 15) * 4;
#pragma unroll
  for (int i = 0; i < 4; i++) {
    float4 v = *(const float4*)&W[(size_t)(r0 + lr + i * 16) * C + c0 + lc4];
    sl[lr + i * 16][lc4 + 0] = v.x;
    sl[lr + i * 16][lc4 + 1] = v.y;
    sl[lr + i * 16][lc4 + 2] = v.z;
    sl[lr + i * 16][lc4 + 3] = v.w;
  }
  __syncthreads();
#pragma unroll
  for (int i = 0; i < 4; i++) {
    int oc = lr + i * 16;
    short4v s;
#pragma unroll
    for (int j = 0; j < 4; j++) s[j] = f2bf(sl[lc4 + j][oc]);
    *(short4v*)&O[(size_t)(c0 + oc) * R + r0 + lc4] = s;
  }
}

// ---------------- gating (fp32 x for exact top-k selection) ----------------
__global__ __launch_bounds__(256) void k_gate(const float* __restrict__ x,
    const float* __restrict__ gw, const float* __restrict__ gb,
    int2* __restrict__ toke, float2* __restrict__ tokw, int* __restrict__ cnt) {
  __shared__ float sg[NEXP * DDIM];
  for (int i = threadIdx.x; i < NEXP * DDIM; i += 256) {
    int e = i >> 10, d = i & (DDIM - 1);
    sg[i] = gw[d * NEXP + e];
  }
  __syncthreads();
  int wave = threadIdx.x >> 6, lane = threadIdx.x & 63;
  int tok0 = blockIdx.x * 32;
  for (int tt = wave; tt < 32; tt += 4) {
    int tok = tok0 + tt;
    float p[NEXP];
#pragma unroll
    for (int e = 0; e < NEXP; e++) p[e] = 0.f;
#pragma unroll
    for (int c = 0; c < 4; c++) {
      int d = c * 256 + lane * 4;
      float4 xv = *(const float4*)&x[(size_t)tok * DDIM + d];
#pragma unroll
      for (int e = 0; e < NEXP; e++) {
        float4 g = *(const float4*)&sg[e * DDIM + d];
        p[e] += xv.x * g.x + xv.y * g.y + xv.z * g.z + xv.w * g.w;
      }
    }
#pragma unroll
    for (int off = 32; off; off >>= 1)
#pragma unroll
      for (int e = 0; e < NEXP; e++) p[e] += __shfl_xor(p[e], off);
    if (lane == 0) {
      float l[NEXP];
#pragma unroll
      for (int e = 0; e < NEXP; e++) l[e] = p[e] + gb[e];
      int i0 = 0;
#pragma unroll
      for (int e = 1; e < NEXP; e++) if (l[e] > l[i0]) i0 = e;
      int i1 = (i0 == 0) ? 1 : 0;
#pragma unroll
      for (int e = 0; e < NEXP; e++) if (e != i0 && l[e] > l[i1]) i1 = e;
      float ex = expf(l[i1] - l[i0]);
      float w0 = 1.f / (1.f + ex);
      toke[tok] = make_int2(i0, i1);
      tokw[tok] = make_float2(w0, 1.f - w0);
      atomicAdd(&cnt[i0], 1);
      atomicAdd(&cnt[i1], 1);
    }
  }
}

// ---------------- routing plan ----------------
__global__ void k_plan(const int* __restrict__ cnt, int* __restrict__ pbase,
                       int* __restrict__ texp) {
  if (threadIdx.x == 0 && blockIdx.x == 0) {
    int base = 0;
    for (int e = 0; e < NEXP; e++) {
      pbase[e] = base;
      int pc = (cnt[e] + BM - 1) & ~(BM - 1);
      for (int t = base / BM; t < (base + pc) / BM; ++t) texp[t] = e;
      base += pc;
    }
    for (int t = base / BM; t < MAXTILES; ++t) texp[t] = -1;
  }
}

__global__ __launch_bounds__(256) void k_scatter(const int2* __restrict__ toke,
    const float2* __restrict__ tokw, const int* __restrict__ pbase,
    int* __restrict__ fill, int* __restrict__ rtok, float* __restrict__ rwgt) {
  int tok = blockIdx.x * 256 + threadIdx.x;
  if (tok >= T_TOK) return;
  int2 te = toke[tok];
  float2 tw = tokw[tok];
  int s0 = atomicAdd(&fill[te.x], 1);
  rtok[pbase[te.x] + s0] = tok; rwgt[pbase[te.x] + s0] = tw.x;
  int s1 = atomicAdd(&fill[te.y], 1);
  rtok[pbase[te.y] + s1] = tok; rwgt[pbase[te.y] + s1] = tw.y;
}

// LDS layout (both GEMMs): linear [256 rows][BK=64 shorts]; logical 16B slot s of
// row r holds global slot (s ^ (r&7))  -> bank-conflict-free frag reads (T2, rule #21).
// Staging: wave w, call i covers rows i*64+w*8 .. +7; lane l -> row +(l>>3), slot l&7.
// K-loop: counted vmcnt (T4) — wait vmcnt(8) for the PREVIOUS tile's 8 loads; this
// tile's 8 prefetch loads stay in flight across both barriers (never drain to 0).

// ---------------- stage 1: h = gelu(x @ w1[e] + b1[e]) ----------------
// grid (HDIM/256 = 16, nt), 512 threads (8 waves, 2x4). w1t = [e][n(H)][k(D)] bf16.
__global__ __launch_bounds__(512) void k_ffn1(const short* __restrict__ xb,
    const short* __restrict__ w1t, const float* __restrict__ b1,
    const int* __restrict__ rtok, const int* __restrict__ texp,
    int tile_base, short* __restrict__ hbuf) {
  int tl = blockIdx.y;
  int tm = tile_base + tl;
  int e = texp[tm];
  if (e < 0) return;
  int n0 = blockIdx.x * BN1;
  const short* W = w1t + (size_t)e * HDIM * DDIM;
  __shared__ short Al[2][BM * BK];
  __shared__ short Bl[2][BM * BK];
  int t = threadIdx.x, wid = t >> 6, lane = t & 63;
  int sr8 = lane >> 3, slot = lane & 7;
  const short* sA[4]; const short* sB[4];
#pragma unroll
  for (int i = 0; i < 4; i++) {
    int r = i * 64 + wid * 8 + sr8;
    int tok = rtok[tm * BM + r]; if (tok < 0) tok = 0;   // pads read row0 (dropped in ffn2)
    sA[i] = xb + (size_t)tok * DDIM + ((slot ^ sr8) * 8);
    sB[i] = W + (size_t)(n0 + r) * DDIM + ((slot ^ sr8) * 8);
  }

  f32x4 acc[8][4];
#pragma unroll
  for (int i = 0; i < 8; i++)
#pragma unroll
    for (int j = 0; j < 4; j++) acc[i][j] = (f32x4){0.f, 0.f, 0.f, 0.f};

  int wm = (wid >> 2) * 128, wn = (wid & 3) * 64;
  int lr = lane & 15, kg = lane >> 4, x7 = lr & 7;

#define STG(b, ko) { \
  gld16(sA[0] + (ko), &Al[b][(0 * 64 + wid * 8) * BK]); \
  gld16(sA[1] + (ko), &Al[b][(1 * 64 + wid * 8) * BK]); \
  gld16(sA[2] + (ko), &Al[b][(2 * 64 + wid * 8) * BK]); \
  gld16(sA[3] + (ko), &Al[b][(3 * 64 + wid * 8) * BK]); \
  gld16(sB[0] + (ko), &Bl[b][(0 * 64 + wid * 8) * BK]); \
  gld16(sB[1] + (ko), &Bl[b][(1 * 64 + wid * 8) * BK]); \
  gld16(sB[2] + (ko), &Bl[b][(2 * 64 + wid * 8) * BK]); \
  gld16(sB[3] + (ko), &Bl[b][(3 * 64 + wid * 8) * BK]); }

#define MFMA_TILE(b) { \
  __builtin_amdgcn_s_setprio(1); \
  _Pragma("unroll") \
  for (int s = 0; s < 2; ++s) { \
    int xo = ((s * 4 + kg) ^ x7) << 3; \
    short8 bg[4]; \
    _Pragma("unroll") \
    for (int j = 0; j < 4; j++) bg[j] = *(short8*)&Bl[b][(wn + j * 16 + lr) * BK + xo]; \
    _Pragma("unroll") \
    for (int i = 0; i < 8; i++) { \
      short8 af = *(short8*)&Al[b][(wm + i * 16 + lr) * BK + xo]; \
      _Pragma("unroll") \
      for (int j = 0; j < 4; j++) \
        acc[i][j] = __builtin_amdgcn_mfma_f32_16x16x32_bf16(af, bg[j], acc[i][j], 0, 0, 0); \
    } \
  } \
  __builtin_amdgcn_s_setprio(0); }

  STG(0, 0);                      // prologue: 8 loads in flight
  const int NK = DDIM / BK;       // 16
  for (int kt = 0; kt < NK; ++kt) {
    int b = kt & 1;
    if (kt + 1 < NK) {
      STG(b ^ 1, (kt + 1) * BK);                          // +8 -> 16 in flight
      asm volatile("s_waitcnt vmcnt(8)" ::: "memory");    // prev tile landed
    } else {
      asm volatile("s_waitcnt vmcnt(0)" ::: "memory");
    }
    __builtin_amdgcn_s_barrier();
    __builtin_amdgcn_sched_barrier(0);
    MFMA_TILE(b);
    __builtin_amdgcn_sched_barrier(0);
    __builtin_amdgcn_s_barrier();   // all waves done reading buf[b] before next STG hits it
    __builtin_amdgcn_sched_barrier(0);
  }

#pragma unroll
  for (int j = 0; j < 4; j++) {
    int gcol = n0 + wn + j * 16 + lr;
    float bias = b1[e * HDIM + gcol];
#pragma unroll
    for (int i = 0; i < 8; i++) {
      int rl = wm + i * 16 + kg * 4;
#pragma unroll
      for (int r = 0; r < 4; r++) {
        float v = acc[i][j][r] + bias;
        v = 0.5f * v * (1.f + erff(v * 0.70710678118f));
        hbuf[(size_t)(tl * BM + rl + r) * HDIM + gcol] = f2bf(v);
      }
    }
  }
}

// ---------------- stage 2: out[tok] += wgt * (h @ w2[e] + b2[e]) ----------------
// grid (DDIM/256 = 4, KS2, nt), 512 threads. w2t = [e][n(D)][k(H)] bf16. Split-K over H.
__global__ __launch_bounds__(512) void k_ffn2(const short* __restrict__ hbuf,
    const short* __restrict__ w2t, const float* __restrict__ b2,
    const int* __restrict__ rtok, const float* __restrict__ rwgt,
    const int* __restrict__ texp, int tile_base, float* __restrict__ out) {
  int tl = blockIdx.z;
  int tm = tile_base + tl;
  int e = texp[tm];
  if (e < 0) return;
  int kc = blockIdx.y;
  int n0 = blockIdx.x * BN1;
  const short* W = w2t + (size_t)e * DDIM * HDIM;
  __shared__ short Al[2][BM * BK];
  __shared__ short Bl[2][BM * BK];
  int t = threadIdx.x, wid = t >> 6, lane = t & 63;
  int sr8 = lane >> 3, slot = lane & 7;
  const int NK = HDIM / BK / KS2;            // 32
  int kbase = kc * NK * BK;
  const short* sA[4]; const short* sB[4];
#pragma unroll
  for (int i = 0; i < 4; i++) {
    int r = i * 64 + wid * 8 + sr8;
    sA[i] = hbuf + (size_t)(tl * BM + r) * HDIM + kbase + ((slot ^ sr8) * 8);
    sB[i] = W + (size_t)(n0 + r) * HDIM + kbase + ((slot ^ sr8) * 8);
  }

  f32x4 acc[8][4];
#pragma unroll
  for (int i = 0; i < 8; i++)
#pragma unroll
    for (int j = 0; j < 4; j++) acc[i][j] = (f32x4){0.f, 0.f, 0.f, 0.f};

  int wm = (wid >> 2) * 128, wn = (wid & 3) * 64;
  int lr = lane & 15, kg = lane >> 4, x7 = lr & 7;

  STG(0, 0);
  for (int kt = 0; kt < NK; ++kt) {
    int b = kt & 1;
    if (kt + 1 < NK) {
      STG(b ^ 1, (kt + 1) * BK);
      asm volatile("s_waitcnt vmcnt(8)" ::: "memory");
    } else {
      asm volatile("s_waitcnt vmcnt(0)" ::: "memory");
    }
    __builtin_amdgcn_s_barrier();
    __builtin_amdgcn_sched_barrier(0);
    MFMA_TILE(b);
    __builtin_amdgcn_sched_barrier(0);
    __builtin_amdgcn_s_barrier();
    __builtin_amdgcn_sched_barrier(0);
  }
#undef STG
#undef MFMA_TILE

#pragma unroll
  for (int j = 0; j < 4; j++) {
    int gcol = n0 + wn + j * 16 + lr;
    float bias = (kc == 0) ? b2[e * DDIM + gcol] : 0.f;
#pragma unroll
    for (int i = 0; i < 8; i++) {
      int rl = wm + i * 16 + kg * 4;
#pragma unroll
      for (int r = 0; r < 4; r++) {
        int grow = tm * BM + rl + r;
        int tok = rtok[grow];
        if (tok >= 0) {
          float v = (acc[i][j][r] + bias) * rwgt[grow];
          atomicAdd(&out[(size_t)tok * DDIM + gcol], v);
        }
      }
    }
  }
}

extern "C" void kernel_launch(void* const* d_in, const int* in_sizes, int n_in,
                              void* d_out, int out_size, void* d_ws, size_t ws_size,
                              hipStream_t stream) {
  const float* x  = (const float*)d_in[0];
  const float* gw = (const float*)d_in[1];
  const float* gb = (const float*)d_in[2];
  const float* w1 = (const float*)d_in[3];
  const float* b1 = (const float*)d_in[4];
  const float* w2 = (const float*)d_in[5];
  const float* b2 = (const float*)d_in[6];
  float* out = (float*)d_out;
  char* ws = (char*)d_ws;

  // ws layout: 1MB header | w1t 67.1MB | w2t 67.1MB | xb 16.8MB | hbuf (chunked)
  int*    cnt   = (int*)(ws + 0);
  int*    fill  = (int*)(ws + 32);
  int*    pbase = (int*)(ws + 64);
  int*    texp  = (int*)(ws + 128);
  int*    rtok  = (int*)(ws + 1024);
  float*  rwgt  = (float*)(ws + 1024 + (size_t)MAXROWS * 4);
  int2*   toke  = (int2*)(ws + 1024 + (size_t)MAXROWS * 8);
  float2* tokw  = (float2*)(ws + 1024 + (size_t)MAXROWS * 8 + (size_t)T_TOK * 8);
  size_t wbytes = (size_t)NEXP * DDIM * HDIM * 2;
  short*  w1t   = (short*)(ws + (1 << 20));
  short*  w2t   = (short*)(ws + (1 << 20) + wbytes);
  short*  xb    = (short*)(ws + (1 << 20) + 2 * wbytes);
  size_t hoff   = (1 << 20) + 2 * wbytes + (size_t)T_TOK * DDIM * 2;
  short*  hbuf  = (short*)(ws + hoff);

  size_t hcap = ws_size > hoff ? ws_size - hoff : 0;
  int tpc = (int)(hcap / ((size_t)BM * HDIM * 2));   // 2MB per tile of h
  if (tpc < 1) return;
  if (tpc > MAXTILES) tpc = MAXTILES;

  hipMemsetAsync(d_out, 0, (size_t)T_TOK * DDIM * 4, stream);
  hipMemsetAsync(ws, 0, 128, stream);
  hipMemsetAsync(rtok, 0xFF, (size_t)MAXROWS * 4, stream);

  k_tr<<<dim3(HDIM / 64, DDIM / 64, NEXP), 256, 0, stream>>>(w1, w1t, DDIM, HDIM);
  k_tr<<<dim3(DDIM / 64, HDIM / 64, NEXP), 256, 0, stream>>>(w2, w2t, HDIM, DDIM);
  k_xb<<<(T_TOK * DDIM) / (256 * 8), 256, 0, stream>>>(x, xb);

  k_gate<<<256, 256, 0, stream>>>(x, gw, gb, toke, tokw, cnt);
  k_plan<<<1, 64, 0, stream>>>(cnt, pbase, texp);
  k_scatter<<<T_TOK / 256, 256, 0, stream>>>(toke, tokw, pbase, fill, rtok, rwgt);

  for (int base = 0; base < MAXTILES; base += tpc) {
    int nt = MAXTILES - base;
    if (nt > tpc) nt = tpc;
    k_ffn1<<<dim3(HDIM / BN1, nt), 512, 0, stream>>>(xb, w1t, b1, rtok, texp, base, hbuf);
    k_ffn2<<<dim3(DDIM / BN1, KS2, nt), 512, 0, stream>>>(hbuf, w2t, b2, rtok, rwgt, texp, base, out);
  }
}

// Round 7
// 1032.685 us; speedup vs baseline: 1.2457x; 1.0298x over previous
//
#include <hip/hip_runtime.h>
#include <math.h>

#define T_TOK 8192
#define DDIM  1024
#define HDIM  4096
#define NEXP  8
#define BM    256
#define BN1   256
#define BK    64                      /* shorts per K-tile */
#define MAXROWS (T_TOK*2 + NEXP*BM)   /* 18432 */
#define MAXTILES (MAXROWS/BM)         /* 72 */
#define KS2   2                       /* split-K factor for ffn2 */

typedef __attribute__((ext_vector_type(8))) short short8;
typedef __attribute__((ext_vector_type(4))) short short4v;
typedef __attribute__((ext_vector_type(4))) float f32x4;

typedef const __attribute__((address_space(1))) unsigned int* gp1_t;
typedef __attribute__((address_space(3))) unsigned int* lp3_t;

__device__ __forceinline__ void gld16(const void* g, void* l) {
  __builtin_amdgcn_global_load_lds((gp1_t)g, (lp3_t)l, 16, 0, 0);
}

__device__ __forceinline__ short f2bf(float f) {
  unsigned u = __float_as_uint(f);
  u += 0x7fffu + ((u >> 16) & 1u);   // RNE
  return (short)(u >> 16);
}

// ---------------- x fp32 -> bf16 ----------------
__global__ __launch_bounds__(256) void k_xb(const float* __restrict__ x,
                                            short* __restrict__ xb) {
  size_t i = ((size_t)blockIdx.x * 256 + threadIdx.x) * 8;
  float4 f0 = *(const float4*)&x[i];
  float4 f1 = *(const float4*)&x[i + 4];
  short8 s;
  s[0]=f2bf(f0.x); s[1]=f2bf(f0.y); s[2]=f2bf(f0.z); s[3]=f2bf(f0.w);
  s[4]=f2bf(f1.x); s[5]=f2bf(f1.y); s[6]=f2bf(f1.z); s[7]=f2bf(f1.w);
  *(short8*)&xb[i] = s;
}

// ---------------- weight transpose + fp32->bf16: wt[e][c][r] = w[e][r][c] ----------------
__global__ __launch_bounds__(256) void k_tr(const float* __restrict__ w,
                                            short* __restrict__ wt, int R, int C) {
  __shared__ float sl[64][65];
  int e = blockIdx.z;
  const float* W = w + (size_t)e * R * C;
  short* O = wt + (size_t)e * R * C;
  int c0 = blockIdx.x * 64, r0 = blockIdx.y * 64;
  int t = threadIdx.x;
  int lr = t >> 4, lc4 = (t & 15) * 4;
#pragma unroll
  for (int i = 0; i < 4; i++) {
    float4 v = *(const float4*)&W[(size_t)(r0 + lr + i * 16) * C + c0 + lc4];
    sl[lr + i * 16][lc4 + 0] = v.x;
    sl[lr + i * 16][lc4 + 1] = v.y;
    sl[lr + i * 16][lc4 + 2] = v.z;
    sl[lr + i * 16][lc4 + 3] = v.w;
  }
  __syncthreads();
#pragma unroll
  for (int i = 0; i < 4; i++) {
    int oc = lr + i * 16;
    short4v s;
#pragma unroll
    for (int j = 0; j < 4; j++) s[j] = f2bf(sl[lc4 + j][oc]);
    *(short4v*)&O[(size_t)(c0 + oc) * R + r0 + lc4] = s;
  }
}

// ---------------- gating (fp32 x for exact top-k selection) ----------------
__global__ __launch_bounds__(256) void k_gate(const float* __restrict__ x,
    const float* __restrict__ gw, const float* __restrict__ gb,
    int2* __restrict__ toke, float2* __restrict__ tokw, int* __restrict__ cnt) {
  __shared__ float sg[NEXP * DDIM];
  for (int i = threadIdx.x; i < NEXP * DDIM; i += 256) {
    int e = i >> 10, d = i & (DDIM - 1);
    sg[i] = gw[d * NEXP + e];
  }
  __syncthreads();
  int wave = threadIdx.x >> 6, lane = threadIdx.x & 63;
  int tok0 = blockIdx.x * 32;
  for (int tt = wave; tt < 32; tt += 4) {
    int tok = tok0 + tt;
    float p[NEXP];
#pragma unroll
    for (int e = 0; e < NEXP; e++) p[e] = 0.f;
#pragma unroll
    for (int c = 0; c < 4; c++) {
      int d = c * 256 + lane * 4;
      float4 xv = *(const float4*)&x[(size_t)tok * DDIM + d];
#pragma unroll
      for (int e = 0; e < NEXP; e++) {
        float4 g = *(const float4*)&sg[e * DDIM + d];
        p[e] += xv.x * g.x + xv.y * g.y + xv.z * g.z + xv.w * g.w;
      }
    }
#pragma unroll
    for (int off = 32; off; off >>= 1)
#pragma unroll
      for (int e = 0; e < NEXP; e++) p[e] += __shfl_xor(p[e], off);
    if (lane == 0) {
      float l[NEXP];
#pragma unroll
      for (int e = 0; e < NEXP; e++) l[e] = p[e] + gb[e];
      int i0 = 0;
#pragma unroll
      for (int e = 1; e < NEXP; e++) if (l[e] > l[i0]) i0 = e;
      int i1 = (i0 == 0) ? 1 : 0;
#pragma unroll
      for (int e = 0; e < NEXP; e++) if (e != i0 && l[e] > l[i1]) i1 = e;
      float ex = expf(l[i1] - l[i0]);
      float w0 = 1.f / (1.f + ex);
      toke[tok] = make_int2(i0, i1);
      tokw[tok] = make_float2(w0, 1.f - w0);
      atomicAdd(&cnt[i0], 1);
      atomicAdd(&cnt[i1], 1);
    }
  }
}

// ---------------- routing plan ----------------
__global__ void k_plan(const int* __restrict__ cnt, int* __restrict__ pbase,
                       int* __restrict__ texp) {
  if (threadIdx.x == 0 && blockIdx.x == 0) {
    int base = 0;
    for (int e = 0; e < NEXP; e++) {
      pbase[e] = base;
      int pc = (cnt[e] + BM - 1) & ~(BM - 1);
      for (int t = base / BM; t < (base + pc) / BM; ++t) texp[t] = e;
      base += pc;
    }
    for (int t = base / BM; t < MAXTILES; ++t) texp[t] = -1;
  }
}

__global__ __launch_bounds__(256) void k_scatter(const int2* __restrict__ toke,
    const float2* __restrict__ tokw, const int* __restrict__ pbase,
    int* __restrict__ fill, int* __restrict__ rtok, float* __restrict__ rwgt) {
  int tok = blockIdx.x * 256 + threadIdx.x;
  if (tok >= T_TOK) return;
  int2 te = toke[tok];
  float2 tw = tokw[tok];
  int s0 = atomicAdd(&fill[te.x], 1);
  rtok[pbase[te.x] + s0] = tok; rwgt[pbase[te.x] + s0] = tw.x;
  int s1 = atomicAdd(&fill[te.y], 1);
  rtok[pbase[te.y] + s1] = tok; rwgt[pbase[te.y] + s1] = tw.y;
}

// ======================= 8-phase grouped GEMM machinery =======================
// LDS: [256 rows][BK=64 shorts], 16B slot s of row r holds global slot s^(r&7).
// 4 phases per K-tile, quadrant (m-half h, n-half q): P0=(0,0) P1=(0,1) P2=(1,1) P3=(1,0).
// Stage per phase (2 gld16/wave): P0:A-half0{slab wid,16+wid} P1:B-q0{bs0,bs0+1}
// P2:B-q1{bs0+4,bs0+5} P3:A-half1{slab 8+wid,24+wid}  (into the dead buffer).
// vmcnt(4) at end of P0,P1,P3 (never lower in steady state).

#define VM4  asm volatile("s_waitcnt vmcnt(4)" ::: "memory")
#define BARR { __builtin_amdgcn_s_barrier(); __builtin_amdgcn_sched_barrier(0); }

#define RD_A(h) { _Pragma("unroll") for (int ii = 0; ii < 4; ii++) \
  _Pragma("unroll") for (int s = 0; s < 2; s++) \
    af[ii][s] = *(short8*)&AL[cur][(wm + (h)*64 + ii*16 + lr) * BK + (((s*4+kg)^x7) << 3)]; }

#define RD_B(q) { _Pragma("unroll") for (int jj = 0; jj < 2; jj++) \
  _Pragma("unroll") for (int s = 0; s < 2; s++) \
    bg[jj][s] = *(short8*)&BL[cur][(wn + (q)*32 + jj*16 + lr) * BK + (((s*4+kg)^x7) << 3)]; }

#define MM(h,q) { __builtin_amdgcn_s_setprio(1); \
  _Pragma("unroll") for (int ii = 0; ii < 4; ii++) \
  _Pragma("unroll") for (int jj = 0; jj < 2; jj++) \
  _Pragma("unroll") for (int s = 0; s < 2; s++) \
    acc[(h)*4+ii][(q)*2+jj] = __builtin_amdgcn_mfma_f32_16x16x32_bf16( \
        af[ii][s], bg[jj][s], acc[(h)*4+ii][(q)*2+jj], 0, 0, 0); \
  __builtin_amdgcn_s_setprio(0); }

#define STG_A0(bf, ko) { gld16(sA[0]+(ko), &AL[bf][(wid*8)*BK]); \
                         gld16(sA[2]+(ko), &AL[bf][(128+wid*8)*BK]); }
#define STG_A1(bf, ko) { gld16(sA[1]+(ko), &AL[bf][(64+wid*8)*BK]); \
                         gld16(sA[3]+(ko), &AL[bf][(192+wid*8)*BK]); }
#define STG_B0(bf, ko) { gld16(sB[0]+(ko), &BL[bf][(bd0)*BK]); \
                         gld16(sB[1]+(ko), &BL[bf][(bd0+8)*BK]); }
#define STG_B1(bf, ko) { gld16(sB[2]+(ko), &BL[bf][(bd0+32)*BK]); \
                         gld16(sB[3]+(ko), &BL[bf][(bd0+40)*BK]); }

#define GEMM8_LOOP(NKv) \
  STG_A0(0, 0); STG_B0(0, 0); STG_B1(0, 0); STG_A1(0, 0); \
  VM4; BARR; \
  for (int t = 0; t < (NKv); ++t) { \
    int cur = t & 1, nxt = cur ^ 1; \
    int kon = ((t + 1 < (NKv)) ? (t + 1) : t) * BK; \
    RD_A(0); RD_B(0); \
    STG_A0(nxt, kon); \
    VM4; BARR; \
    MM(0, 0); \
    RD_B(1); \
    STG_B0(nxt, kon); \
    VM4; BARR; \
    MM(0, 1); \
    RD_A(1); \
    STG_B1(nxt, kon); \
    BARR; \
    MM(1, 1); \
    RD_B(0); \
    STG_A1(nxt, kon); \
    VM4; BARR; \
    MM(1, 0); \
  } \
  asm volatile("s_waitcnt vmcnt(0)" ::: "memory");

// ---------------- stage 1: h = gelu(x @ w1[e] + b1[e]) ----------------
// grid (HDIM/256 = 16, nt), 512 threads (8 waves, 2x4). w1t = [e][n(H)][k(D)] bf16.
__global__ __launch_bounds__(512) void k_ffn1(const short* __restrict__ xb,
    const short* __restrict__ w1t, const float* __restrict__ b1,
    const int* __restrict__ rtok, const int* __restrict__ texp,
    int tile_base, short* __restrict__ hbuf) {
  int tl = blockIdx.y;
  int tm = tile_base + tl;
  int e = texp[tm];
  if (e < 0) return;
  int n0 = blockIdx.x * BN1;
  const short* W = w1t + (size_t)e * HDIM * DDIM;
  __shared__ short AL[2][BM * BK];
  __shared__ short BL[2][BM * BK];
  int t = threadIdx.x, wid = t >> 6, lane = t & 63;
  int sr8 = lane >> 3, slot = lane & 7;
  int swz = (slot ^ sr8) * 8;
  const short* sA[4]; const short* sB[4];
#pragma unroll
  for (int i = 0; i < 4; i++) {
    int r = i * 64 + wid * 8 + sr8;
    int tok = rtok[tm * BM + r]; if (tok < 0) tok = 0;   // pads read row0 (dropped in ffn2)
    sA[i] = xb + (size_t)tok * DDIM + swz;
  }
  int bs0 = (wid >> 1) * 8 + ((2 * wid) & 3);   // first q0 B-slab for this wave
  int bd0 = bs0 * 8;
  {
    int rb = bd0 + sr8;
    sB[0] = W + (size_t)(n0 + rb) * DDIM + swz;
    sB[1] = W + (size_t)(n0 + rb + 8) * DDIM + swz;
    sB[2] = W + (size_t)(n0 + rb + 32) * DDIM + swz;
    sB[3] = W + (size_t)(n0 + rb + 40) * DDIM + swz;
  }

  f32x4 acc[8][4];
#pragma unroll
  for (int i = 0; i < 8; i++)
#pragma unroll
    for (int j = 0; j < 4; j++) acc[i][j] = (f32x4){0.f, 0.f, 0.f, 0.f};
  short8 af[4][2], bg[2][2];

  int wm = (wid >> 2) * 128, wn = (wid & 3) * 64;
  int lr = lane & 15, kg = lane >> 4, x7 = lr & 7;

  GEMM8_LOOP(DDIM / BK)

#pragma unroll
  for (int j = 0; j < 4; j++) {
    int gcol = n0 + wn + j * 16 + lr;
    float bias = b1[e * HDIM + gcol];
#pragma unroll
    for (int i = 0; i < 8; i++) {
      int rl = wm + i * 16 + kg * 4;
#pragma unroll
      for (int r = 0; r < 4; r++) {
        float v = acc[i][j][r] + bias;
        v = 0.5f * v * (1.f + erff(v * 0.70710678118f));
        hbuf[(size_t)(tl * BM + rl + r) * HDIM + gcol] = f2bf(v);
      }
    }
  }
}

// ---------------- stage 2: out[tok] += wgt * (h @ w2[e] + b2[e]) ----------------
// grid (DDIM/256 = 4, KS2, nt), 512 threads. w2t = [e][n(D)][k(H)] bf16. Split-K over H.
__global__ __launch_bounds__(512) void k_ffn2(const short* __restrict__ hbuf,
    const short* __restrict__ w2t, const float* __restrict__ b2,
    const int* __restrict__ rtok, const float* __restrict__ rwgt,
    const int* __restrict__ texp, int tile_base, float* __restrict__ out) {
  int tl = blockIdx.z;
  int tm = tile_base + tl;
  int e = texp[tm];
  if (e < 0) return;
  int kc = blockIdx.y;
  int n0 = blockIdx.x * BN1;
  const short* W = w2t + (size_t)e * DDIM * HDIM;
  __shared__ short AL[2][BM * BK];
  __shared__ short BL[2][BM * BK];
  int t = threadIdx.x, wid = t >> 6, lane = t & 63;
  int sr8 = lane >> 3, slot = lane & 7;
  int swz = (slot ^ sr8) * 8;
  const int NK = HDIM / BK / KS2;            // 32
  int kbase = kc * NK * BK;
  const short* sA[4]; const short* sB[4];
#pragma unroll
  for (int i = 0; i < 4; i++) {
    int r = i * 64 + wid * 8 + sr8;
    sA[i] = hbuf + (size_t)(tl * BM + r) * HDIM + kbase + swz;
  }
  int bs0 = (wid >> 1) * 8 + ((2 * wid) & 3);
  int bd0 = bs0 * 8;
  {
    int rb = bd0 + sr8;
    sB[0] = W + (size_t)(n0 + rb) * HDIM + kbase + swz;
    sB[1] = W + (size_t)(n0 + rb + 8) * HDIM + kbase + swz;
    sB[2] = W + (size_t)(n0 + rb + 32) * HDIM + kbase + swz;
    sB[3] = W + (size_t)(n0 + rb + 40) * HDIM + kbase + swz;
  }

  f32x4 acc[8][4];
#pragma unroll
  for (int i = 0; i < 8; i++)
#pragma unroll
    for (int j = 0; j < 4; j++) acc[i][j] = (f32x4){0.f, 0.f, 0.f, 0.f};
  short8 af[4][2], bg[2][2];

  int wm = (wid >> 2) * 128, wn = (wid & 3) * 64;
  int lr = lane & 15, kg = lane >> 4, x7 = lr & 7;

  GEMM8_LOOP(NK)

#pragma unroll
  for (int j = 0; j < 4; j++) {
    int gcol = n0 + wn + j * 16 + lr;
    float bias = (kc == 0) ? b2[e * DDIM + gcol] : 0.f;
#pragma unroll
    for (int i = 0; i < 8; i++) {
      int rl = wm + i * 16 + kg * 4;
#pragma unroll
      for (int r = 0; r < 4; r++) {
        int grow = tm * BM + rl + r;
        int tok = rtok[grow];
        if (tok >= 0) {
          float v = (acc[i][j][r] + bias) * rwgt[grow];
          atomicAdd(&out[(size_t)tok * DDIM + gcol], v);
        }
      }
    }
  }
}

extern "C" void kernel_launch(void* const* d_in, const int* in_sizes, int n_in,
                              void* d_out, int out_size, void* d_ws, size_t ws_size,
                              hipStream_t stream) {
  const float* x  = (const float*)d_in[0];
  const float* gw = (const float*)d_in[1];
  const float* gb = (const float*)d_in[2];
  const float* w1 = (const float*)d_in[3];
  const float* b1 = (const float*)d_in[4];
  const float* w2 = (const float*)d_in[5];
  const float* b2 = (const float*)d_in[6];
  float* out = (float*)d_out;
  char* ws = (char*)d_ws;

  // ws layout: 1MB header | w1t 67.1MB | w2t 67.1MB | xb 16.8MB | hbuf (chunked)
  int*    cnt   = (int*)(ws + 0);
  int*    fill  = (int*)(ws + 32);
  int*    pbase = (int*)(ws + 64);
  int*    texp  = (int*)(ws + 128);
  int*    rtok  = (int*)(ws + 1024);
  float*  rwgt  = (float*)(ws + 1024 + (size_t)MAXROWS * 4);
  int2*   toke  = (int2*)(ws + 1024 + (size_t)MAXROWS * 8);
  float2* tokw  = (float2*)(ws + 1024 + (size_t)MAXROWS * 8 + (size_t)T_TOK * 8);
  size_t wbytes = (size_t)NEXP * DDIM * HDIM * 2;
  short*  w1t   = (short*)(ws + (1 << 20));
  short*  w2t   = (short*)(ws + (1 << 20) + wbytes);
  short*  xb    = (short*)(ws + (1 << 20) + 2 * wbytes);
  size_t hoff   = (1 << 20) + 2 * wbytes + (size_t)T_TOK * DDIM * 2;
  short*  hbuf  = (short*)(ws + hoff);

  size_t hcap = ws_size > hoff ? ws_size - hoff : 0;
  int tpc = (int)(hcap / ((size_t)BM * HDIM * 2));   // 2MB per tile of h
  if (tpc < 1) return;
  if (tpc > MAXTILES) tpc = MAXTILES;

  hipMemsetAsync(d_out, 0, (size_t)T_TOK * DDIM * 4, stream);
  hipMemsetAsync(ws, 0, 128, stream);
  hipMemsetAsync(rtok, 0xFF, (size_t)MAXROWS * 4, stream);

  k_tr<<<dim3(HDIM / 64, DDIM / 64, NEXP), 256, 0, stream>>>(w1, w1t, DDIM, HDIM);
  k_tr<<<dim3(DDIM / 64, HDIM / 64, NEXP), 256, 0, stream>>>(w2, w2t, HDIM, DDIM);
  k_xb<<<(T_TOK * DDIM) / (256 * 8), 256, 0, stream>>>(x, xb);

  k_gate<<<256, 256, 0, stream>>>(x, gw, gb, toke, tokw, cnt);
  k_plan<<<1, 64, 0, stream>>>(cnt, pbase, texp);
  k_scatter<<<T_TOK / 256, 256, 0, stream>>>(toke, tokw, pbase, fill, rtok, rwgt);

  for (int base = 0; base < MAXTILES; base += tpc) {
    int nt = MAXTILES - base;
    if (nt > tpc) nt = tpc;
    k_ffn1<<<dim3(HDIM / BN1, nt), 512, 0, stream>>>(xb, w1t, b1, rtok, texp, base, hbuf);
    k_ffn2<<<dim3(DDIM / BN1, KS2, nt), 512, 0, stream>>>(hbuf, w2t, b2, rtok, rwgt, texp, base, out);
  }
}